// Round 2
// baseline (275.878 us; speedup 1.0000x reference)
//
#include <hip/hip_runtime.h>

#define NB 4
#define NS 4096
#define NDIN 1024
#define ND 64

typedef __attribute__((ext_vector_type(4))) float f32x4;
typedef __attribute__((ext_vector_type(8))) short s16x8;
typedef __attribute__((ext_vector_type(4))) short s16x4;

__device__ __forceinline__ unsigned short f2bf(float f) {
  union { float f; unsigned u; } x; x.f = f;
  unsigned r = x.u + 0x7fffu + ((x.u >> 16) & 1u);
  return (unsigned short)(r >> 16);
}

// ---- kernel 0: W -> bf16, transposed to [mat][col][k] for B-fragment reads
__global__ __launch_bounds__(256) void prep_w_kernel(
    const float* __restrict__ Wq, const float* __restrict__ Wk,
    const float* __restrict__ Wv, unsigned short* __restrict__ wt) {
  int idx = blockIdx.x * 256 + threadIdx.x;  // grid sized exactly 3*64*1024
  int m = idx >> 16;
  int r = idx & 65535;
  int c = r >> 10;
  int k = r & 1023;
  const float* W = (m == 0) ? Wq : (m == 1) ? Wk : Wv;
  wt[idx] = f2bf(W[k * ND + c]);
}

// ---- kernel 0b: mask int32 [B][S][S] -> bitmask, 1 bit per element
__global__ __launch_bounds__(256) void mask_pack_kernel(
    const int* __restrict__ mask, unsigned char* __restrict__ bits) {
  const int idx = blockIdx.x * 256 + threadIdx.x;  // 8,388,608 threads, 1 byte each
  const int4* mp = reinterpret_cast<const int4*>(mask) + (size_t)idx * 2;
  const int4 a = mp[0];
  const int4 c = mp[1];
  unsigned v = (unsigned)(a.x != 0) | ((unsigned)(a.y != 0) << 1) |
               ((unsigned)(a.z != 0) << 2) | ((unsigned)(a.w != 0) << 3) |
               ((unsigned)(c.x != 0) << 4) | ((unsigned)(c.y != 0) << 5) |
               ((unsigned)(c.z != 0) << 6) | ((unsigned)(c.w != 0) << 7);
  bits[idx] = (unsigned char)v;
}

// ---- kernel 1: projection X[16384][1024] @ W[1024][64] + b -> bf16
// y==0: q row-major, y==1: k row-major, y==2: v transposed [b][64][4096]
__global__ __launch_bounds__(256) void proj_kernel(
    const float* __restrict__ Xq, const float* __restrict__ Xk, const float* __restrict__ Xv,
    const float* __restrict__ bq, const float* __restrict__ bk, const float* __restrict__ bv,
    const unsigned short* __restrict__ wt_all,
    unsigned short* __restrict__ q_o, unsigned short* __restrict__ k_o,
    unsigned short* __restrict__ vt_o) {
  const int y = blockIdx.y;
  const float* __restrict__ X = (y == 0) ? Xq : (y == 1) ? Xk : Xv;
  const float* __restrict__ bias = (y == 0) ? bq : (y == 1) ? bk : bv;
  const unsigned short* __restrict__ wt = wt_all + y * (ND * NDIN);
  const int row0 = blockIdx.x * 64;
  const int tid = threadIdx.x;
  const int lane = tid & 63;
  const int w = tid >> 6;
  const int ql = lane & 15;
  const int grp = lane >> 4;

  __shared__ unsigned short abuf[64][40];  // 80B row stride: 2-way bank alias (free)

  f32x4 acc[4] = {};

  for (int k0 = 0; k0 < NDIN; k0 += 32) {
    #pragma unroll
    for (int j = 0; j < 2; ++j) {
      int idx = tid + 256 * j;       // 0..511
      int rr = idx >> 3;             // 64 rows
      int c4 = idx & 7;              // 8 float4 per row
      const float4 xv = *reinterpret_cast<const float4*>(
          &X[(size_t)(row0 + rr) * NDIN + k0 + c4 * 4]);
      s16x4 hv;
      hv[0] = (short)f2bf(xv.x);
      hv[1] = (short)f2bf(xv.y);
      hv[2] = (short)f2bf(xv.z);
      hv[3] = (short)f2bf(xv.w);
      *reinterpret_cast<s16x4*>(&abuf[rr][c4 * 4]) = hv;
    }
    __syncthreads();
    const s16x8 a = *reinterpret_cast<const s16x8*>(&abuf[16 * w + ql][grp * 8]);
    #pragma unroll
    for (int nt = 0; nt < 4; ++nt) {
      const s16x8 bfr = *reinterpret_cast<const s16x8*>(
          &wt[(size_t)(ql + 16 * nt) * NDIN + k0 + grp * 8]);
      acc[nt] = __builtin_amdgcn_mfma_f32_16x16x32_bf16(a, bfr, acc[nt], 0, 0, 0);
    }
    __syncthreads();
  }

  const int b = row0 >> 12;
  const int s0 = row0 & 4095;
  #pragma unroll
  for (int nt = 0; nt < 4; ++nt) {
    const int col = ql + 16 * nt;
    const float bia = bias[col];
    #pragma unroll
    for (int r = 0; r < 4; ++r) {
      const int rr = 16 * w + grp * 4 + r;  // C layout: col=lane&15, row=(lane>>4)*4+r
      const unsigned short h = f2bf(acc[nt][r] + bia);
      if (y == 0) {
        q_o[(size_t)(row0 + rr) * ND + col] = h;
      } else if (y == 1) {
        k_o[(size_t)(row0 + rr) * ND + col] = h;
      } else {
        vt_o[(size_t)b * ND * NS + (size_t)col * NS + (s0 + rr)] = h;
      }
    }
  }
}

// ---- kernel 2: flash attention, swapped QK^T, 16 q-rows/block, 4-way kv-split,
//      bitmask, register-double-buffered K + mask prefetch
__global__ __launch_bounds__(256, 4) void attn_kernel(
    const unsigned short* __restrict__ qm, const unsigned short* __restrict__ km,
    const unsigned short* __restrict__ vt, const unsigned char* __restrict__ mbits,
    float* __restrict__ out) {
  const int b = blockIdx.y;
  const int q0 = blockIdx.x * 16;
  const int tid = threadIdx.x;
  const int lane = tid & 63;
  const int w = tid >> 6;
  const int ql = lane & 15;   // q col (softmax state)
  const int grp = lane >> 4;  // 0..3

  __shared__ unsigned short p_lds[4][16][72];  // per-wave P, 144B stride
  __shared__ float Lm[4][16];
  __shared__ float Ll[4][16];
  __shared__ float accbuf[4][16][64];

  // Q as B-operand fragments (held for whole kernel)
  const size_t qrow = (size_t)(b * NS + q0 + ql) * ND;
  const s16x8 qf0 = *reinterpret_cast<const s16x8*>(qm + qrow + grp * 8);
  const s16x8 qf1 = *reinterpret_cast<const s16x8*>(qm + qrow + 32 + grp * 8);

  f32x4 acc_o[4] = {};
  float m_i = -INFINITY;
  float l_i = 0.f;

  const size_t kbase = (size_t)b * NS * ND;
  const size_t vbase = (size_t)b * ND * NS;
  const unsigned char* __restrict__ mrow =
      mbits + (size_t)(b * NS + q0 + ql) * (NS / 8) + w * 128;
  const int kv00 = w * 1024;  // wave-private kv quarter

  auto kload = [&](s16x8 (&kf)[8], int t) {
    #pragma unroll
    for (int mt = 0; mt < 4; ++mt) {
      const unsigned short* kp =
          km + kbase + (size_t)(kv00 + t * 64 + 16 * mt + ql) * ND + grp * 8;
      kf[2 * mt]     = *reinterpret_cast<const s16x8*>(kp);
      kf[2 * mt + 1] = *reinterpret_cast<const s16x8*>(kp + 32);
    }
  };

  s16x8 kA[8], kB[8];
  unsigned long long mA = 0, mB = 0;
  kload(kA, 0);
  mA = *reinterpret_cast<const unsigned long long*>(mrow);

  auto body = [&](s16x8 (&kc)[8], unsigned long long mc,
                  s16x8 (&kn)[8], unsigned long long& mn, int t) {
    // ---- QK^T (scores^T: lane ql = q, rows = kv)
    f32x4 s4[4];
    __builtin_amdgcn_s_setprio(1);
    #pragma unroll
    for (int mt = 0; mt < 4; ++mt) {
      f32x4 s = {0.f, 0.f, 0.f, 0.f};
      s = __builtin_amdgcn_mfma_f32_16x16x32_bf16(kc[2 * mt], qf0, s, 0, 0, 0);
      s = __builtin_amdgcn_mfma_f32_16x16x32_bf16(kc[2 * mt + 1], qf1, s, 0, 0, 0);
      s4[mt] = s;
    }
    __builtin_amdgcn_s_setprio(0);

    // ---- prefetch next tile's K-frags + mask word (latency hides under softmax)
    if (t < 15) {
      kload(kn, t + 1);
      mn = *reinterpret_cast<const unsigned long long*>(mrow + (t + 1) * 8);
    }

    // ---- mask apply from bitmask: bit (kv-kv0) of mc
    float sc[16];
    #pragma unroll
    for (int mt = 0; mt < 4; ++mt) {
      const unsigned mb = (unsigned)((mc >> (16 * mt + grp * 4)) & 0xFull);
      #pragma unroll
      for (int r = 0; r < 4; ++r) {
        sc[4 * mt + r] = (mb & (1u << r)) ? s4[mt][r] * 0.125f : -1e30f;
      }
    }

    // ---- column(q)-softmax: tree max + 2 shuffles across grp
    float t0 = fmaxf(fmaxf(sc[0], sc[1]), fmaxf(sc[2], sc[3]));
    float t1 = fmaxf(fmaxf(sc[4], sc[5]), fmaxf(sc[6], sc[7]));
    float t2 = fmaxf(fmaxf(sc[8], sc[9]), fmaxf(sc[10], sc[11]));
    float t3 = fmaxf(fmaxf(sc[12], sc[13]), fmaxf(sc[14], sc[15]));
    float tm = fmaxf(fmaxf(t0, t1), fmaxf(t2, t3));
    tm = fmaxf(tm, __shfl_xor(tm, 16));
    tm = fmaxf(tm, __shfl_xor(tm, 32));
    const float new_m = fmaxf(m_i, tm);
    const float alpha = __expf(m_i - new_m);  // first tile: exp(-inf)=0
    #pragma unroll
    for (int r = 0; r < 16; ++r) sc[r] = __expf(sc[r] - new_m);
    float u0 = (sc[0] + sc[1]) + (sc[2] + sc[3]);
    float u1 = (sc[4] + sc[5]) + (sc[6] + sc[7]);
    float u2 = (sc[8] + sc[9]) + (sc[10] + sc[11]);
    float u3 = (sc[12] + sc[13]) + (sc[14] + sc[15]);
    float ssum = (u0 + u1) + (u2 + u3);
    ssum += __shfl_xor(ssum, 16);
    ssum += __shfl_xor(ssum, 32);
    l_i = l_i * alpha + ssum;
    m_i = new_m;

    // ---- P -> wave-private LDS as bf16 (A-operand layout [q][kv])
    #pragma unroll
    for (int mt = 0; mt < 4; ++mt) {
      s16x4 pk;
      pk[0] = (short)f2bf(sc[4 * mt + 0]);
      pk[1] = (short)f2bf(sc[4 * mt + 1]);
      pk[2] = (short)f2bf(sc[4 * mt + 2]);
      pk[3] = (short)f2bf(sc[4 * mt + 3]);
      *reinterpret_cast<s16x4*>(&p_lds[w][ql][16 * mt + grp * 4]) = pk;
    }

    // ---- rescale accumulator: alpha indexed by q=lane; out rows are grp*4+r
    #pragma unroll
    for (int r = 0; r < 4; ++r) {
      const float ar = __shfl(alpha, grp * 4 + r);
      acc_o[0][r] *= ar;
      acc_o[1][r] *= ar;
      acc_o[2][r] *= ar;
      acc_o[3][r] *= ar;
    }

    // ---- PV: A = P from LDS, B = V^T from global (L2-resident)
    const int kv0 = kv00 + t * 64;
    #pragma unroll
    for (int ks = 0; ks < 2; ++ks) {
      const s16x8 pa = *reinterpret_cast<const s16x8*>(&p_lds[w][ql][ks * 32 + grp * 8]);
      __builtin_amdgcn_s_setprio(1);
      #pragma unroll
      for (int nt = 0; nt < 4; ++nt) {
        const s16x8 vb = *reinterpret_cast<const s16x8*>(
            vt + vbase + (size_t)(ql + 16 * nt) * NS + kv0 + ks * 32 + grp * 8);
        acc_o[nt] = __builtin_amdgcn_mfma_f32_16x16x32_bf16(pa, vb, acc_o[nt], 0, 0, 0);
      }
      __builtin_amdgcn_s_setprio(0);
    }
  };

  for (int tt = 0; tt < 16; tt += 2) {
    body(kA, mA, kB, mB, tt);
    body(kB, mB, kA, mA, tt + 1);
  }

  // ---- combine the 4 kv-split partials (flash LSE-combine)
  if (lane < 16) {
    Lm[w][lane] = m_i;
    Ll[w][lane] = l_i;
  }
  __syncthreads();

  #pragma unroll
  for (int r = 0; r < 4; ++r) {
    const int qq = grp * 4 + r;
    const float m0 = Lm[0][qq], m1 = Lm[1][qq], m2 = Lm[2][qq], m3 = Lm[3][qq];
    const float M = fmaxf(fmaxf(m0, m1), fmaxf(m2, m3));
    const float denom = Ll[0][qq] * __expf(m0 - M) + Ll[1][qq] * __expf(m1 - M) +
                        Ll[2][qq] * __expf(m2 - M) + Ll[3][qq] * __expf(m3 - M);
    const float f = __expf(Lm[w][qq] - M) / denom;
    #pragma unroll
    for (int nt = 0; nt < 4; ++nt) {
      accbuf[w][qq][ql + 16 * nt] = acc_o[nt][r] * f;
    }
  }
  __syncthreads();

  {
    const int qq = tid >> 4;
    const int v4 = tid & 15;
    f32x4 s = *reinterpret_cast<const f32x4*>(&accbuf[0][qq][v4 * 4]);
    #pragma unroll
    for (int w2 = 1; w2 < 4; ++w2)
      s += *reinterpret_cast<const f32x4*>(&accbuf[w2][qq][v4 * 4]);
    *reinterpret_cast<f32x4*>(&out[(size_t)(b * NS + q0 + qq) * ND + v4 * 4]) = s;
  }
}

extern "C" void kernel_launch(void* const* d_in, const int* in_sizes, int n_in,
                              void* d_out, int out_size, void* d_ws, size_t ws_size,
                              hipStream_t stream) {
  const float* query = (const float*)d_in[0];
  const float* key   = (const float*)d_in[1];
  const float* value = (const float*)d_in[2];
  const int*   mask  = (const int*)d_in[3];
  const float* Wq = (const float*)d_in[4];
  const float* bq = (const float*)d_in[5];
  const float* Wk = (const float*)d_in[6];
  const float* bk = (const float*)d_in[7];
  const float* Wv = (const float*)d_in[8];
  const float* bv = (const float*)d_in[9];
  float* out = (float*)d_out;

  char* ws = (char*)d_ws;
  unsigned short* wt  = (unsigned short*)(ws);                          // 384 KB
  unsigned short* qb  = (unsigned short*)(ws + 393216);                 // 2 MB
  unsigned short* kb  = (unsigned short*)(ws + 393216 + 2097152);       // 2 MB
  unsigned short* vtb = (unsigned short*)(ws + 393216 + 2 * 2097152);   // 2 MB
  unsigned char*  mbits = (unsigned char*)(ws + 393216 + 3 * 2097152);  // 8 MB

  prep_w_kernel<<<dim3(768), dim3(256), 0, stream>>>(Wq, Wk, Wv, wt);
  mask_pack_kernel<<<dim3(32768), dim3(256), 0, stream>>>(mask, mbits);
  proj_kernel<<<dim3(256, 3), dim3(256), 0, stream>>>(query, key, value,
                                                      bq, bk, bv, wt, qb, kb, vtb);
  attn_kernel<<<dim3(256, NB), dim3(256), 0, stream>>>(qb, kb, vtb, mbits, out);
}

// Round 4
// 171.202 us; speedup vs baseline: 1.6114x; 1.6114x over previous
//
#include <hip/hip_runtime.h>

#define NB 4
#define NS 4096
#define NDIN 1024
#define ND 64

typedef __attribute__((ext_vector_type(4))) float f32x4;
typedef __attribute__((ext_vector_type(8))) short s16x8;
typedef __attribute__((ext_vector_type(4))) short s16x4;

__device__ __forceinline__ unsigned short f2bf(float f) {
  union { float f; unsigned u; } x; x.f = f;
  unsigned r = x.u + 0x7fffu + ((x.u >> 16) & 1u);
  return (unsigned short)(r >> 16);
}

__device__ __forceinline__ void gload16(const void* g, void* l) {
  __builtin_amdgcn_global_load_lds(
      (const __attribute__((address_space(1))) void*)g,
      (__attribute__((address_space(3))) void*)l, 16, 0, 0);
}

// ---- kernel 0: W -> bf16, transposed to [mat][col][k] for B-fragment reads
__global__ __launch_bounds__(256) void prep_w_kernel(
    const float* __restrict__ Wq, const float* __restrict__ Wk,
    const float* __restrict__ Wv, unsigned short* __restrict__ wt) {
  int idx = blockIdx.x * 256 + threadIdx.x;  // grid sized exactly 3*64*1024
  int m = idx >> 16;
  int r = idx & 65535;
  int c = r >> 10;
  int k = r & 1023;
  const float* W = (m == 0) ? Wq : (m == 1) ? Wk : Wv;
  wt[idx] = f2bf(W[k * ND + c]);
}

// ---- kernel 0b: mask int32 [B][S][S] -> bitmask, 1 bit per element
__global__ __launch_bounds__(256) void mask_pack_kernel(
    const int* __restrict__ mask, unsigned char* __restrict__ bits) {
  const int idx = blockIdx.x * 256 + threadIdx.x;  // 8,388,608 threads, 1 byte each
  const int4* mp = reinterpret_cast<const int4*>(mask) + (size_t)idx * 2;
  const int4 a = mp[0];
  const int4 c = mp[1];
  unsigned v = (unsigned)(a.x != 0) | ((unsigned)(a.y != 0) << 1) |
               ((unsigned)(a.z != 0) << 2) | ((unsigned)(a.w != 0) << 3) |
               ((unsigned)(c.x != 0) << 4) | ((unsigned)(c.y != 0) << 5) |
               ((unsigned)(c.z != 0) << 6) | ((unsigned)(c.w != 0) << 7);
  bits[idx] = (unsigned char)v;
}

// ---- kernel 1: projection X[16384][1024] @ W[1024][64] + b -> bf16
// y==0: q row-major, y==1: k row-major, y==2: v transposed [b][64][4096]
__global__ __launch_bounds__(256) void proj_kernel(
    const float* __restrict__ Xq, const float* __restrict__ Xk, const float* __restrict__ Xv,
    const float* __restrict__ bq, const float* __restrict__ bk, const float* __restrict__ bv,
    const unsigned short* __restrict__ wt_all,
    unsigned short* __restrict__ q_o, unsigned short* __restrict__ k_o,
    unsigned short* __restrict__ vt_o) {
  const int y = blockIdx.y;
  const float* __restrict__ X = (y == 0) ? Xq : (y == 1) ? Xk : Xv;
  const float* __restrict__ bias = (y == 0) ? bq : (y == 1) ? bk : bv;
  const unsigned short* __restrict__ wt = wt_all + y * (ND * NDIN);
  const int row0 = blockIdx.x * 64;
  const int tid = threadIdx.x;
  const int lane = tid & 63;
  const int w = tid >> 6;
  const int ql = lane & 15;
  const int grp = lane >> 4;

  __shared__ unsigned short abuf[64][40];  // 80B row stride: 2-way bank alias (free)

  f32x4 acc[4] = {};

  for (int k0 = 0; k0 < NDIN; k0 += 32) {
    #pragma unroll
    for (int j = 0; j < 2; ++j) {
      int idx = tid + 256 * j;       // 0..511
      int rr = idx >> 3;             // 64 rows
      int c4 = idx & 7;              // 8 float4 per row
      const float4 xv = *reinterpret_cast<const float4*>(
          &X[(size_t)(row0 + rr) * NDIN + k0 + c4 * 4]);
      s16x4 hv;
      hv[0] = (short)f2bf(xv.x);
      hv[1] = (short)f2bf(xv.y);
      hv[2] = (short)f2bf(xv.z);
      hv[3] = (short)f2bf(xv.w);
      *reinterpret_cast<s16x4*>(&abuf[rr][c4 * 4]) = hv;
    }
    __syncthreads();
    const s16x8 a = *reinterpret_cast<const s16x8*>(&abuf[16 * w + ql][grp * 8]);
    #pragma unroll
    for (int nt = 0; nt < 4; ++nt) {
      const s16x8 bfr = *reinterpret_cast<const s16x8*>(
          &wt[(size_t)(ql + 16 * nt) * NDIN + k0 + grp * 8]);
      acc[nt] = __builtin_amdgcn_mfma_f32_16x16x32_bf16(a, bfr, acc[nt], 0, 0, 0);
    }
    __syncthreads();
  }

  const int b = row0 >> 12;
  const int s0 = row0 & 4095;
  #pragma unroll
  for (int nt = 0; nt < 4; ++nt) {
    const int col = ql + 16 * nt;
    const float bia = bias[col];
    #pragma unroll
    for (int r = 0; r < 4; ++r) {
      const int rr = 16 * w + grp * 4 + r;  // C layout: col=lane&15, row=(lane>>4)*4+r
      const unsigned short h = f2bf(acc[nt][r] + bia);
      if (y == 0) {
        q_o[(size_t)(row0 + rr) * ND + col] = h;
      } else if (y == 1) {
        k_o[(size_t)(row0 + rr) * ND + col] = h;
      } else {
        vt_o[(size_t)b * ND * NS + (size_t)col * NS + (s0 + rr)] = h;
      }
    }
  }
}

// ---- kernel 2: flash attention, LDS-staged K/V (double-buffered, XOR-swizzled),
//      4 waves share kv tile / own 16 q each, kv-split 4 across blocks
__global__ __launch_bounds__(256, 4) void attn_kernel(
    const unsigned short* __restrict__ qm, const unsigned short* __restrict__ km,
    const unsigned short* __restrict__ vt, const unsigned char* __restrict__ mbits,
    float* __restrict__ opart, float* __restrict__ ml) {
  __shared__ unsigned short ksm[2][4096];  // [buf][64 kv][64 d], 128B rows, swizzled
  __shared__ unsigned short vsm[2][4096];  // [buf][64 d][64 kv], 128B rows, swizzled
  __shared__ unsigned short psm[4096];     // 4 waves x [16 q][64 kv], swizzled

  const int bid = blockIdx.x;
  const int combo = bid & 15;   // (b,split): bid%8 = XCD -> each XCD sees 2 combos
  const int qblk = bid >> 4;
  const int b = combo >> 2;
  const int split = combo & 3;
  const int q0 = qblk * 64;
  const int kv00 = split * 1024;

  const int tid = threadIdx.x;
  const int lane = tid & 63;
  const int w = tid >> 6;
  const int ql = lane & 15;
  const int grp = lane >> 4;

  // shared swizzle: byte ^= ((row&7)<<4) within 128-B rows.
  // fragment byte offsets — XOR applied to the FULL column (rule 21: same involution
  // both sides; round-3 bug was `^swz` then `+64`, which carries into the row bits)
  const int swz = (ql & 7) << 4;
  const int fK0 = ql * 128 + ((grp * 16) ^ swz);        // k-bytes 0..15 of col pair
  const int fK1 = ql * 128 + ((grp * 16 + 64) ^ swz);   // k-bytes 64..79

  // staging source offsets (constant per lane): LDS linear o -> pre-swizzled src
  int oK0, oK1, oV0, oV1;
  {
    const int o0 = w * 2048 + lane * 16;
    const int o1 = o0 + 1024;
    oK0 = o0 ^ (((o0 >> 7) & 7) << 4);
    oK1 = o1 ^ (((o1 >> 7) & 7) << 4);
    const int d0 = o0 >> 7, c0 = o0 & 127;
    const int d1 = o1 >> 7, c1 = o1 & 127;
    oV0 = d0 * 8192 + (c0 ^ ((d0 & 7) << 4));
    oV1 = d1 * 8192 + (c1 ^ ((d1 & 7) << 4));
  }

  const char* kg = (const char*)(km + (size_t)b * NS * ND + (size_t)kv00 * ND);
  const char* vg = (const char*)(vt + (size_t)b * ND * NS + kv00);
  char* const klds = (char*)&ksm[0][0] + w * 2048;
  char* const vlds = (char*)&vsm[0][0] + w * 2048;
  char* const pw = (char*)&psm[0] + w * 2048;

  // Q as B-operand fragments (held for whole kernel)
  const size_t qrow = (size_t)(b * NS + q0 + w * 16 + ql) * ND;
  const s16x8 qf0 = *reinterpret_cast<const s16x8*>(qm + qrow + grp * 8);
  const s16x8 qf1 = *reinterpret_cast<const s16x8*>(qm + qrow + 32 + grp * 8);

  const unsigned char* mrow =
      mbits + (size_t)(b * NS + q0 + w * 16 + ql) * (NS / 8) + split * 128;

  f32x4 acc[4] = {};
  float m_i = -INFINITY;
  float l_i = 0.f;

  auto stage = [&](int t, int buf) {
    const char* kt = kg + (size_t)t * 8192;
    const char* vtb = vg + (size_t)t * 128;
    gload16(kt + oK0, klds + buf * 8192);
    gload16(kt + oK1, klds + buf * 8192 + 1024);
    gload16(vtb + oV0, vlds + buf * 8192);
    gload16(vtb + oV1, vlds + buf * 8192 + 1024);
  };

  stage(0, 0);
  unsigned long long mA = *reinterpret_cast<const unsigned long long*>(mrow);
  asm volatile("s_waitcnt vmcnt(0)" ::: "memory");
  __syncthreads();

  for (int t = 0; t < 16; ++t) {
    const int cur = t & 1;
    if (t < 15) stage(t + 1, cur ^ 1);
    unsigned long long mB =
        (t < 15) ? *reinterpret_cast<const unsigned long long*>(mrow + (t + 1) * 8) : 0ull;

    const char* kread = (const char*)&ksm[0][0] + cur * 8192;
    const char* vread = (const char*)&vsm[0][0] + cur * 8192;

    // ---- QK^T: A = K (LDS), B = Q (regs) -> S^T[kv][q], lane: q=ql, kv=16mt+grp*4+r
    f32x4 s4[4];
    __builtin_amdgcn_s_setprio(1);
    #pragma unroll
    for (int mt = 0; mt < 4; ++mt) {
      const s16x8 kf0 = *reinterpret_cast<const s16x8*>(kread + mt * 2048 + fK0);
      const s16x8 kf1 = *reinterpret_cast<const s16x8*>(kread + mt * 2048 + fK1);
      f32x4 s = {0.f, 0.f, 0.f, 0.f};
      s = __builtin_amdgcn_mfma_f32_16x16x32_bf16(kf0, qf0, s, 0, 0, 0);
      s = __builtin_amdgcn_mfma_f32_16x16x32_bf16(kf1, qf1, s, 0, 0, 0);
      s4[mt] = s;
    }
    __builtin_amdgcn_s_setprio(0);

    // ---- mask from bitmask word
    float sc[16];
    #pragma unroll
    for (int mt = 0; mt < 4; ++mt) {
      const unsigned mb = (unsigned)((mA >> (16 * mt + grp * 4)) & 0xFull);
      #pragma unroll
      for (int r = 0; r < 4; ++r) {
        sc[4 * mt + r] = (mb & (1u << r)) ? s4[mt][r] * 0.125f : -1e30f;
      }
    }

    // ---- online softmax along kv (tree + 2 shuffles across grp)
    float t0 = fmaxf(fmaxf(sc[0], sc[1]), fmaxf(sc[2], sc[3]));
    float t1 = fmaxf(fmaxf(sc[4], sc[5]), fmaxf(sc[6], sc[7]));
    float t2 = fmaxf(fmaxf(sc[8], sc[9]), fmaxf(sc[10], sc[11]));
    float t3 = fmaxf(fmaxf(sc[12], sc[13]), fmaxf(sc[14], sc[15]));
    float tm = fmaxf(fmaxf(t0, t1), fmaxf(t2, t3));
    tm = fmaxf(tm, __shfl_xor(tm, 16));
    tm = fmaxf(tm, __shfl_xor(tm, 32));
    const float new_m = fmaxf(m_i, tm);
    const float alpha = __expf(m_i - new_m);
    #pragma unroll
    for (int r = 0; r < 16; ++r) sc[r] = __expf(sc[r] - new_m);
    float u0 = (sc[0] + sc[1]) + (sc[2] + sc[3]);
    float u1 = (sc[4] + sc[5]) + (sc[6] + sc[7]);
    float u2 = (sc[8] + sc[9]) + (sc[10] + sc[11]);
    float u3 = (sc[12] + sc[13]) + (sc[14] + sc[15]);
    float ssum = (u0 + u1) + (u2 + u3);
    ssum += __shfl_xor(ssum, 16);
    ssum += __shfl_xor(ssum, 32);
    l_i = l_i * alpha + ssum;
    m_i = new_m;

    // ---- P -> wave-private LDS (A-layout [q][kv], swizzled, full-XOR both sides)
    #pragma unroll
    for (int mt = 0; mt < 4; ++mt) {
      s16x4 pk;
      pk[0] = (short)f2bf(sc[4 * mt + 0]);
      pk[1] = (short)f2bf(sc[4 * mt + 1]);
      pk[2] = (short)f2bf(sc[4 * mt + 2]);
      pk[3] = (short)f2bf(sc[4 * mt + 3]);
      *reinterpret_cast<s16x4*>(pw + ql * 128 + ((mt * 32 + grp * 8) ^ swz)) = pk;
    }

    // ---- rescale accumulator (alpha lives at lane q=ql; acc rows are q=grp*4+r)
    #pragma unroll
    for (int r = 0; r < 4; ++r) {
      const float ar = __shfl(alpha, grp * 4 + r);
      acc[0][r] *= ar;
      acc[1][r] *= ar;
      acc[2][r] *= ar;
      acc[3][r] *= ar;
    }

    // ---- PV: A = P (LDS), B = V^T (LDS) -> O[q][d]; V frag cols == fK0/fK1
    #pragma unroll
    for (int ks = 0; ks < 2; ++ks) {
      const s16x8 pa = *reinterpret_cast<const s16x8*>(
          pw + ql * 128 + ((ks * 64 + grp * 16) ^ swz));
      const int fV = ks ? fK1 : fK0;
      __builtin_amdgcn_s_setprio(1);
      #pragma unroll
      for (int nt = 0; nt < 4; ++nt) {
        const s16x8 vb = *reinterpret_cast<const s16x8*>(vread + nt * 2048 + fV);
        acc[nt] = __builtin_amdgcn_mfma_f32_16x16x32_bf16(pa, vb, acc[nt], 0, 0, 0);
      }
      __builtin_amdgcn_s_setprio(0);
    }

    asm volatile("s_waitcnt vmcnt(0)" ::: "memory");
    __syncthreads();
    mA = mB;
  }

  // ---- write split partials: O rows + (m,l)
  const int qg = b * NS + q0 + w * 16;
  float* obase = opart + ((size_t)split * (NB * NS) + qg) * 64;
  #pragma unroll
  for (int nt = 0; nt < 4; ++nt) {
    #pragma unroll
    for (int r = 0; r < 4; ++r) {
      obase[(size_t)(grp * 4 + r) * 64 + ql + 16 * nt] = acc[nt][r];
    }
  }
  if (grp == 0) {
    float* mlp = ml + ((size_t)split * (NB * NS) + qg + ql) * 2;
    mlp[0] = m_i;
    mlp[1] = l_i;
  }
}

// ---- kernel 3: LSE-combine the 4 kv-split partials
__global__ __launch_bounds__(256) void combine_kernel(
    const float* __restrict__ opart, const float* __restrict__ ml,
    float* __restrict__ out) {
  const int idx = blockIdx.x * 256 + threadIdx.x;  // 262144 threads
  const int q = idx >> 4;
  const int dc = (idx & 15) * 4;
  const float2 a0 = *reinterpret_cast<const float2*>(ml + (size_t)q * 2);
  const float2 a1 = *reinterpret_cast<const float2*>(ml + (size_t)(16384 + q) * 2);
  const float2 a2 = *reinterpret_cast<const float2*>(ml + (size_t)(32768 + q) * 2);
  const float2 a3 = *reinterpret_cast<const float2*>(ml + (size_t)(49152 + q) * 2);
  const float M = fmaxf(fmaxf(a0.x, a1.x), fmaxf(a2.x, a3.x));
  const float w0 = __expf(a0.x - M), w1 = __expf(a1.x - M);
  const float w2 = __expf(a2.x - M), w3 = __expf(a3.x - M);
  const float inv = 1.f / (a0.y * w0 + a1.y * w1 + a2.y * w2 + a3.y * w3);
  f32x4 o = (*reinterpret_cast<const f32x4*>(opart + (size_t)q * 64 + dc)) * w0;
  o += (*reinterpret_cast<const f32x4*>(opart + ((size_t)16384 + q) * 64 + dc)) * w1;
  o += (*reinterpret_cast<const f32x4*>(opart + ((size_t)32768 + q) * 64 + dc)) * w2;
  o += (*reinterpret_cast<const f32x4*>(opart + ((size_t)49152 + q) * 64 + dc)) * w3;
  o *= inv;
  *reinterpret_cast<f32x4*>(out + (size_t)q * 64 + dc) = o;
}

extern "C" void kernel_launch(void* const* d_in, const int* in_sizes, int n_in,
                              void* d_out, int out_size, void* d_ws, size_t ws_size,
                              hipStream_t stream) {
  const float* query = (const float*)d_in[0];
  const float* key   = (const float*)d_in[1];
  const float* value = (const float*)d_in[2];
  const int*   mask  = (const int*)d_in[3];
  const float* Wq = (const float*)d_in[4];
  const float* bq = (const float*)d_in[5];
  const float* Wk = (const float*)d_in[6];
  const float* bk = (const float*)d_in[7];
  const float* Wv = (const float*)d_in[8];
  const float* bv = (const float*)d_in[9];
  float* out = (float*)d_out;

  char* ws = (char*)d_ws;
  unsigned short* wt    = (unsigned short*)(ws);               // 384 KB
  unsigned short* qb    = (unsigned short*)(ws + 393216);      // 2 MB
  unsigned short* kb    = (unsigned short*)(ws + 2490368);     // 2 MB
  unsigned short* vtb   = (unsigned short*)(ws + 4587520);     // 2 MB
  unsigned char*  mbits = (unsigned char*)(ws + 6684672);      // 8 MB
  float*          opart = (float*)(ws + 15073280);             // 16 MB
  float*          mlb   = (float*)(ws + 31850496);             // 512 KB

  prep_w_kernel<<<dim3(768), dim3(256), 0, stream>>>(Wq, Wk, Wv, wt);
  mask_pack_kernel<<<dim3(32768), dim3(256), 0, stream>>>(mask, mbits);
  proj_kernel<<<dim3(256, 3), dim3(256), 0, stream>>>(query, key, value,
                                                      bq, bk, bv, wt, qb, kb, vtb);
  attn_kernel<<<dim3(1024), dim3(256), 0, stream>>>(qb, kb, vtb, mbits, opart, mlb);
  combine_kernel<<<dim3(1024), dim3(256), 0, stream>>>(opart, mlb, out);
}